// Round 4
// baseline (275.765 us; speedup 1.0000x reference)
//
#include <hip/hip_runtime.h>

// GCLSTM (ChebConv K=1 => edge_index unused; every node is an independent LSTM
// with shared weights). Fused persistent kernel, bf16 MFMA recurrence:
//   g = [H(64) | x(3) | 0-pad] @ [Theta; W_x; 0]   K=96, via mfma_f32_16x16x32_bf16
// R3: 500 blocks x 40 nodes (grid 250 < 256 CUs was the occupancy limiter:
//     1 wave/SIMD, no latency hiding). 2 independent blocks/CU.
// R4: double-buffered A-tile -> ONE __syncthreads per timestep (was 2).
//     GEMM reads Al[buf]; gates write H_new + x(ts+1) into Al[buf^1].
// LDS: 53.2KB (Theta) + 2x10KB (A dbuf) = 73.2KB/block -> 2 blocks/CU (146/160).

#define T_STEPS 64
#define N_NODES 20000
#define F_INP   3
#define HD      64
#define G4      256    // 4*HD
#define KP      104    // padded bf16 K-stride: rows 0..63 H, 64..66 x, 67..95 zero
#define BM      40     // valid nodes per block
#define BMP     48     // padded rows in A-tile (3 M-tiles)
#define MT      3      // M-tiles per block
#define NBLK    500    // N_NODES / BM
#define NTHR    256

typedef __attribute__((ext_vector_type(8))) short bf16x8;
typedef __attribute__((ext_vector_type(4))) float f32x4;

__device__ __forceinline__ unsigned short f2bf(float f) {
    union { float f; unsigned u; } v; v.f = f;
    unsigned r = v.u + 0x7FFFu + ((v.u >> 16) & 1u);   // RNE
    return (unsigned short)(r >> 16);
}
__device__ __forceinline__ float sigf(float x) {
    return __builtin_amdgcn_rcpf(1.0f + __expf(-x));
}
__device__ __forceinline__ float tanhf_(float x) {
    return 2.0f * __builtin_amdgcn_rcpf(1.0f + __expf(-2.0f * x)) - 1.0f;
}

__global__ __launch_bounds__(NTHR, 2)
void gclstm_main(const float* __restrict__ x_seq,    // [T][N][3]
                 const float* __restrict__ W_x,      // [3][256]
                 const float* __restrict__ Theta,    // [64][256]
                 const float* __restrict__ b_conv,   // [256]
                 const float* __restrict__ b_gate,   // [256]
                 const float* __restrict__ w_ci,     // [64]
                 const float* __restrict__ w_cf,     // [64]
                 const float* __restrict__ w_co,     // [64]
                 float* __restrict__ partial)        // [NBLK][HD]
{
    __shared__ __align__(16) unsigned short Bl[G4 * KP];      // Theta^T bf16 [n][k] 53.2KB
    __shared__ __align__(16) unsigned short Al[2][BMP * KP];  // H/x bf16 dbuf, 2x10KB

    const int t   = threadIdx.x;
    const int blk = blockIdx.x;
    const int n0  = blk * BM;
    const int w   = t >> 6;        // wave 0..3
    const int l   = t & 63;        // lane
    const int ln  = l & 15;        // lane&15: A-row / B-col / C-col index
    const int lg  = l >> 4;        // lane group: k-octet select / C-row group
    const int d   = w * 16 + ln;   // this lane's hidden dim (gates phase)

    // ---- zero LDS (k-pad + node-pad rows must be 0 in BOTH buffers) ----
    for (int i = t; i < (G4 * KP) / 2; i += NTHR) ((unsigned*)Bl)[i] = 0u;
    for (int i = t; i < BMP * KP; i += NTHR) ((unsigned*)&Al[0][0])[i] = 0u;  // both bufs
    __syncthreads();
    for (int i = t; i < HD * G4; i += NTHR) {          // Theta [k][n] -> Bl[n][k]
        int k = i >> 8, n = i & 255;
        Bl[n * KP + k] = f2bf(Theta[i]);
    }
    for (int i = t; i < F_INP * G4; i += NTHR) {       // W_x rows -> k = 64..66
        int k = 64 + (i >> 8), n = i & 255;
        Bl[n * KP + k] = f2bf(W_x[i]);
    }
    if (t < BM * F_INP)                                 // x(ts=0) -> Al[0], k=64..66
        Al[0][(t / 3) * KP + 64 + (t % 3)] = f2bf(x_seq[(size_t)(n0) * F_INP + t]);
    __syncthreads();

    // ---- Theta fragments -> registers, once (B-frag: lane&15 = col) ----
    bf16x8 Breg[4][3];
    #pragma unroll
    for (int g = 0; g < 4; ++g)
        #pragma unroll
        for (int ks = 0; ks < 3; ++ks)
            Breg[g][ks] = *reinterpret_cast<const bf16x8*>(
                &Bl[(g * 64 + d) * KP + ks * 32 + lg * 8]);

    // fp32 bias + peephole for this lane's dim (exact, outside the bf16 GEMM)
    const float bI = b_conv[d]       + b_gate[d];
    const float bF = b_conv[64 + d]  + b_gate[64 + d];
    const float bC = b_conv[128 + d] + b_gate[128 + d];
    const float bO = b_conv[192 + d] + b_gate[192 + d];
    const float wci_ = w_ci[d], wcf_ = w_cf[d], wco_ = w_co[d];

    float creg[MT][4];
    #pragma unroll
    for (int mi = 0; mi < MT; ++mi)
        #pragma unroll
        for (int r = 0; r < 4; ++r) creg[mi][r] = 0.0f;

    float hsum = 0.0f;   // final-H per-lane node sum (exact fp32)

    for (int ts = 0; ts < T_STEPS; ++ts) {
        const unsigned short* Ard = &Al[ts & 1][0];       // GEMM read buffer
        unsigned short*       Awr = &Al[(ts & 1) ^ 1][0]; // gates/x write buffer

        // ---- GEMM: acc[mi][g] = A(H|x) . B(Theta|W_x), fp32 accumulate ----
        f32x4 acc[MT][4];
        #pragma unroll
        for (int mi = 0; mi < MT; ++mi)
            #pragma unroll
            for (int g = 0; g < 4; ++g)
                acc[mi][g] = (f32x4){0.f, 0.f, 0.f, 0.f};

        #pragma unroll
        for (int ks = 0; ks < 3; ++ks) {
            bf16x8 Ar[MT];
            #pragma unroll
            for (int mi = 0; mi < MT; ++mi)
                Ar[mi] = *reinterpret_cast<const bf16x8*>(
                    &Ard[(mi * 16 + ln) * KP + ks * 32 + lg * 8]);
            #pragma unroll
            for (int mi = 0; mi < MT; ++mi)
                #pragma unroll
                for (int g = 0; g < 4; ++g)
                    acc[mi][g] = __builtin_amdgcn_mfma_f32_16x16x32_bf16(
                        Ar[mi], Breg[g][ks], acc[mi][g], 0, 0, 0);
        }
        // no barrier: writes below target the OTHER buffer (disjoint LDS)

        // ---- gates (fp32). C/D layout: col=lane&15 (dim d), row=lg*4+r (node) ----
        #pragma unroll
        for (int mi = 0; mi < MT; ++mi) {
            #pragma unroll
            for (int r = 0; r < 4; ++r) {
                const int node = mi * 16 + lg * 4 + r;
                float C  = creg[mi][r];
                float gi = acc[mi][0][r] + bI + wci_ * C;
                float gf = acc[mi][1][r] + bF + wcf_ * C;
                float gc = acc[mi][2][r] + bC;
                float I  = sigf(gi);
                float Fg = sigf(gf);
                float Tc = tanhf_(gc);
                float Cn = Fg * C + I * Tc;
                float O  = sigf(acc[mi][3][r] + bO + wco_ * Cn);
                float Hn = O * tanhf_(Cn);
                creg[mi][r] = Cn;
                if (node < BM) {
                    Awr[node * KP + d] = f2bf(Hn);     // H_new -> next buf, k=0..63
                    if (ts == T_STEPS - 1) hsum += Hn; // valid nodes only
                }
            }
        }
        // stage x(ts+1) into next buf, k-rows 64..66 (disjoint from H columns)
        if (ts + 1 < T_STEPS && t < BM * F_INP)
            Awr[(t / 3) * KP + 64 + (t % 3)] =
                f2bf(x_seq[(size_t)((ts + 1) * N_NODES + n0) * F_INP + t]);
        __syncthreads();   // single barrier: next-buf writes visible before next GEMM
    }

    // ---- final-H node sum: lanes l, l+16, l+32, l+48 share dim d ----
    hsum += __shfl_down(hsum, 32);
    hsum += __shfl_down(hsum, 16);
    if (l < 16) partial[blk * HD + d] = hsum;   // d = w*16 + l
}

__global__ __launch_bounds__(NTHR, 1)
void reduce_head(const float* __restrict__ partial,  // [NBLK][HD]
                 const float* __restrict__ W_lin,    // [64][2]
                 const float* __restrict__ b_lin,    // [2]
                 float* __restrict__ out)            // [2]
{
    __shared__ float sums[4][HD];
    __shared__ float emb[HD];
    const int t = threadIdx.x;      // 256 threads
    const int d = t & 63;
    const int p = t >> 6;           // 4-way split of the block dimension
    float s = 0.0f;
    for (int b = p; b < NBLK; b += 4)
        s += partial[b * HD + d];   // 64-lane coalesced per iteration
    sums[p][d] = s;
    __syncthreads();
    if (t < HD)
        emb[t] = (sums[0][t] + sums[1][t] + sums[2][t] + sums[3][t])
                 * (1.0f / (float)N_NODES);
    __syncthreads();
    if (t < 2) {
        float acc = b_lin[t];
        #pragma unroll
        for (int dd = 0; dd < HD; ++dd)
            acc = fmaf(emb[dd], W_lin[dd * 2 + t], acc);
        out[t] = acc;
    }
}

extern "C" void kernel_launch(void* const* d_in, const int* in_sizes, int n_in,
                              void* d_out, int out_size, void* d_ws, size_t ws_size,
                              hipStream_t stream) {
    const float* x_seq  = (const float*)d_in[0];
    // d_in[1] = edge_index (int64) -- unused: ChebConv K=1 has no neighbor aggregation
    const float* W_x    = (const float*)d_in[2];
    const float* Theta  = (const float*)d_in[3];
    const float* b_conv = (const float*)d_in[4];
    const float* b_gate = (const float*)d_in[5];
    const float* w_ci   = (const float*)d_in[6];
    const float* w_cf   = (const float*)d_in[7];
    const float* w_co   = (const float*)d_in[8];
    const float* W_lin  = (const float*)d_in[9];
    const float* b_lin  = (const float*)d_in[10];

    float* out     = (float*)d_out;
    float* partial = (float*)d_ws;   // NBLK*HD floats = 128000 B

    gclstm_main<<<NBLK, NTHR, 0, stream>>>(x_seq, W_x, Theta, b_conv, b_gate,
                                           w_ci, w_cf, w_co, partial);
    reduce_head<<<1, NTHR, 0, stream>>>(partial, W_lin, b_lin, out);
}

// Round 10
// 252.834 us; speedup vs baseline: 1.0907x; 1.0907x over previous
//
#include <hip/hip_runtime.h>

// GCLSTM (ChebConv K=1 => edge_index unused; every node is an independent LSTM
// with shared weights). Fused persistent kernel, bf16 MFMA recurrence:
//   g = [H(64) | x(3) | 0-pad] @ [Theta; W_x; 0]   K=96, via mfma_f32_16x16x32_bf16
// R5: BM 40->16 (one M-tile), grid = 1250 -> 4-6 blocks/CU; Theta staged via
//   13.3KB LDS chunks -> steady LDS 20KB/block; bias folded into MFMA acc
//   init; exp2-scale folded into weights; x pointer walk.
// R6: reduce_head vectorized (float4, 16-way split, coalesced 16B/lane).
// R7: T14 async-STAGE split for x(ts+1): global load ISSUED at top of the
//   timestep (hides ~200-500cy L2 latency under GEMM+gates), LDS write at the
//   end.
// R8-R10: resubmissions (infra failures; kernel audited, unchanged).

#define T_STEPS 64
#define N_NODES 20000
#define F_INP   3
#define HD      64
#define G4      256    // 4*HD
#define KP      104    // padded bf16 K-stride: 0..63 H, 64..66 x, 67..95 zero
#define BM      16     // nodes per block == one M-tile
#define NBLK    1250   // N_NODES / BM
#define NTHR    256

typedef __attribute__((ext_vector_type(8))) short bf16x8;
typedef __attribute__((ext_vector_type(4))) float f32x4;

#define SC1 (-1.4426950408889634f)   // -log2(e)      : sigmoid gates (i,f,o)
#define SC2 (-2.8853900817779268f)   // -2*log2(e)    : tanh pre-scale (c gate)

__device__ __forceinline__ unsigned short f2bf(float f) {
    union { float f; unsigned u; } v; v.f = f;
    unsigned r = v.u + 0x7FFFu + ((v.u >> 16) & 1u);   // RNE
    return (unsigned short)(r >> 16);
}

__global__ __launch_bounds__(NTHR, 4)
void gclstm_main(const float* __restrict__ x_seq,    // [T][N][3]
                 const float* __restrict__ W_x,      // [3][256]
                 const float* __restrict__ Theta,    // [64][256]
                 const float* __restrict__ b_conv,   // [256]
                 const float* __restrict__ b_gate,   // [256]
                 const float* __restrict__ w_ci,     // [64]
                 const float* __restrict__ w_cf,     // [64]
                 const float* __restrict__ w_co,     // [64]
                 float* __restrict__ partial)        // [NBLK][HD]
{
    __shared__ __align__(16) unsigned short Ts[HD * KP];     // 13312 B staging
    __shared__ __align__(16) unsigned short Al[2][BM * KP];  // 2 x 3328 B dbuf

    const int t   = threadIdx.x;
    const int blk = blockIdx.x;
    const int n0  = blk * BM;
    const int w   = t >> 6;        // wave 0..3 -> dim group
    const int l   = t & 63;        // lane
    const int ln  = l & 15;        // A-row / B-col / C-col index
    const int lg  = l >> 4;        // k-octet select / C-row group
    const int d   = w * 16 + ln;   // this lane's hidden dim

    // ---- zero LDS: Ts (k-pad rows must stay 0), Al both buffers ----
    for (int i = t; i < (HD * KP) / 2; i += NTHR) ((unsigned*)Ts)[i] = 0u;
    for (int i = t; i < BM * KP; i += NTHR) ((unsigned*)&Al[0][0])[i] = 0u;
    __syncthreads();

    // x(ts=0) -> Al[0] k-rows 64..66 (visibility covered by chunk barriers)
    if (t < BM * F_INP)
        Al[0][(t / 3) * KP + 64 + (t % 3)] = f2bf(x_seq[(size_t)n0 * F_INP + t]);

    // ---- Theta/W_x -> Breg via 4 gate-chunks (scale folded into bf16) ----
    bf16x8 Breg[4][3];
    #pragma unroll
    for (int g = 0; g < 4; ++g) {
        const float sc = (g == 2) ? SC2 : SC1;
        __syncthreads();                       // prior chunk's Breg reads done
        for (int i = t; i < HD * 64; i += NTHR) {          // Theta cols g*64..+63
            int k = i >> 6, j = i & 63;
            Ts[j * KP + k] = f2bf(sc * Theta[k * G4 + g * 64 + j]);
        }
        for (int i = t; i < F_INP * 64; i += NTHR) {       // W_x rows -> k 64..66
            int k = i >> 6, j = i & 63;
            Ts[j * KP + 64 + k] = f2bf(sc * W_x[k * G4 + g * 64 + j]);
        }
        __syncthreads();
        #pragma unroll
        for (int ks = 0; ks < 3; ++ks)
            Breg[g][ks] = *reinterpret_cast<const bf16x8*>(
                &Ts[d * KP + ks * 32 + lg * 8]);
    }

    // scaled biases + peephole (fp32, exact; scale folded per gate)
    const float bI = SC1 * (b_conv[d]       + b_gate[d]);
    const float bF = SC1 * (b_conv[64 + d]  + b_gate[64 + d]);
    const float bC = SC2 * (b_conv[128 + d] + b_gate[128 + d]);
    const float bO = SC1 * (b_conv[192 + d] + b_gate[192 + d]);
    const float wci_ = SC1 * w_ci[d], wcf_ = SC1 * w_cf[d], wco_ = SC1 * w_co[d];

    float creg[4] = {0.f, 0.f, 0.f, 0.f};
    float hsum = 0.f;
    const float* xp = x_seq + (size_t)N_NODES * F_INP + (size_t)n0 * F_INP; // ts=1

    for (int ts = 0; ts < T_STEPS; ++ts) {
        const unsigned short* Ard = &Al[ts & 1][0];
        unsigned short*       Awr = &Al[(ts & 1) ^ 1][0];

        // T14 split, part 1: ISSUE next-timestep x load now; latency hides
        // under the GEMM + gates below. LDS write happens after gates.
        float xv = 0.0f;
        if (ts + 1 < T_STEPS && t < BM * F_INP) xv = xp[t];

        // ---- GEMM with bias-in-acc init ----
        f32x4 acc[4];
        acc[0] = (f32x4){bI, bI, bI, bI};
        acc[1] = (f32x4){bF, bF, bF, bF};
        acc[2] = (f32x4){bC, bC, bC, bC};
        acc[3] = (f32x4){bO, bO, bO, bO};

        #pragma unroll
        for (int ks = 0; ks < 3; ++ks) {
            bf16x8 Ar = *reinterpret_cast<const bf16x8*>(
                &Ard[ln * KP + ks * 32 + lg * 8]);
            #pragma unroll
            for (int g = 0; g < 4; ++g)
                acc[g] = __builtin_amdgcn_mfma_f32_16x16x32_bf16(
                    Ar, Breg[g][ks], acc[g], 0, 0, 0);
        }
        // no barrier: gates write the OTHER buffer

        // ---- gates. acc holds PRE-SCALED g: sig(x)=rcp(1+exp2(x')), ----
        // ---- tanh(x)=2*rcp(1+exp2(x''))-1. C/D: col=ln (dim), row=lg*4+r ----
        #pragma unroll
        for (int r = 0; r < 4; ++r) {
            const int node = lg * 4 + r;
            float C   = creg[r];
            float giS = fmaf(wci_, C, acc[0][r]);
            float gfS = fmaf(wcf_, C, acc[1][r]);
            float I   = __builtin_amdgcn_rcpf(1.0f + exp2f(giS));
            float Fg  = __builtin_amdgcn_rcpf(1.0f + exp2f(gfS));
            float Tc  = fmaf(2.0f, __builtin_amdgcn_rcpf(1.0f + exp2f(acc[2][r])), -1.0f);
            float Cn  = fmaf(Fg, C, I * Tc);
            float goS = fmaf(wco_, Cn, acc[3][r]);
            float O   = __builtin_amdgcn_rcpf(1.0f + exp2f(goS));
            float th  = fmaf(2.0f, __builtin_amdgcn_rcpf(1.0f + exp2f(SC2 * Cn)), -1.0f);
            float Hn  = O * th;
            creg[r] = Cn;
            Awr[node * KP + d] = f2bf(Hn);
            if (ts == T_STEPS - 1) hsum += Hn;
        }
        // T14 split, part 2: write the (already-arrived) x value to LDS.
        if (ts + 1 < T_STEPS && t < BM * F_INP)
            Awr[(t / 3) * KP + 64 + (t % 3)] = f2bf(xv);
        xp += (size_t)N_NODES * F_INP;
        __syncthreads();   // next-buf writes visible before next GEMM
    }

    // ---- final-H node sum: lanes l, l+16, l+32, l+48 share dim d ----
    hsum += __shfl_down(hsum, 32);
    hsum += __shfl_down(hsum, 16);
    if (l < 16) partial[blk * HD + d] = hsum;   // d = w*16 + ln
}

__global__ __launch_bounds__(NTHR, 1)
void reduce_head(const float* __restrict__ partial,  // [NBLK][HD]
                 const float* __restrict__ W_lin,    // [64][2]
                 const float* __restrict__ b_lin,    // [2]
                 float* __restrict__ out)            // [2]
{
    // float4 over dims: thread owns dim-quad dq, strides blocks by 16.
    // Wave reads 1KB contiguous per iteration (16B/lane, coalesced).
    __shared__ float4 sums[16][16];   // [p][dq]
    __shared__ float emb[HD];
    const int t  = threadIdx.x;       // 256 threads
    const int dq = t & 15;            // dim quad: dims dq*4 .. dq*4+3
    const int p  = t >> 4;            // 16-way split over node-blocks
    const float4* p4 = (const float4*)partial;   // [NBLK][16] float4
    float4 a = {0.f, 0.f, 0.f, 0.f};
    #pragma unroll 4
    for (int b = p; b < NBLK; b += 16) {
        float4 v = p4[b * 16 + dq];
        a.x += v.x; a.y += v.y; a.z += v.z; a.w += v.w;
    }
    sums[p][dq] = a;
    __syncthreads();
    if (t < 16) {                     // t == dq: fold 16 partial quads
        float4 s = sums[0][t];
        #pragma unroll
        for (int q = 1; q < 16; ++q) {
            float4 v = sums[q][t];
            s.x += v.x; s.y += v.y; s.z += v.z; s.w += v.w;
        }
        const float inv = 1.0f / (float)N_NODES;
        emb[t * 4 + 0] = s.x * inv;
        emb[t * 4 + 1] = s.y * inv;
        emb[t * 4 + 2] = s.z * inv;
        emb[t * 4 + 3] = s.w * inv;
    }
    __syncthreads();
    if (t < 2) {
        float acc = b_lin[t];
        #pragma unroll
        for (int dd = 0; dd < HD; ++dd)
            acc = fmaf(emb[dd], W_lin[dd * 2 + t], acc);
        out[t] = acc;
    }
}

extern "C" void kernel_launch(void* const* d_in, const int* in_sizes, int n_in,
                              void* d_out, int out_size, void* d_ws, size_t ws_size,
                              hipStream_t stream) {
    const float* x_seq  = (const float*)d_in[0];
    // d_in[1] = edge_index (int64) -- unused: ChebConv K=1 has no neighbor aggregation
    const float* W_x    = (const float*)d_in[2];
    const float* Theta  = (const float*)d_in[3];
    const float* b_conv = (const float*)d_in[4];
    const float* b_gate = (const float*)d_in[5];
    const float* w_ci   = (const float*)d_in[6];
    const float* w_cf   = (const float*)d_in[7];
    const float* w_co   = (const float*)d_in[8];
    const float* W_lin  = (const float*)d_in[9];
    const float* b_lin  = (const float*)d_in[10];

    float* out     = (float*)d_out;
    float* partial = (float*)d_ws;   // NBLK*HD floats = 320000 B

    gclstm_main<<<NBLK, NTHR, 0, stream>>>(x_seq, W_x, Theta, b_conv, b_gate,
                                           w_ci, w_cf, w_co, partial);
    reduce_head<<<1, NTHR, 0, stream>>>(partial, W_lin, b_lin, out);
}

// Round 12
// 199.986 us; speedup vs baseline: 1.3789x; 1.2643x over previous
//
#include <hip/hip_runtime.h>

// GCLSTM (ChebConv K=1 => edge_index unused; every node is an independent LSTM
// with shared weights). Fused persistent kernel, bf16 MFMA recurrence:
//   g = [H(64) | x(3) | 0-pad] @ [Theta; W_x; 0]   K=96, via mfma_f32_16x16x32_bf16
// R5: BM=16 (one M-tile), grid 1250; Theta staged via 13.3KB LDS chunks
//     (steady LDS 20KB); bias-in-acc; exp2-scale folded into weights; x ptr walk.
// R6: reduce_head vectorized (float4, 16-way split).
// R7: T14 async split for x(ts+1) (load at top, LDS write at end).
// R11 (R10 showed VALU-pipe saturation at 78% busy, dur unchanged from R4
//     despite 1.7x occupancy):
//   * SWAPPED MFMA operands: mfma(Theta-frag, H-frag). Breg/Ar loads are
//     unchanged (A/B fragment lane-mappings are structurally identical);
//     output becomes D[dim][node]: lane holds node=lane&15, dims db+{0..3}.
//     => H_new write is 4 CONSECUTIVE bf16: 2x v_cvt_pk (via __bf16 casts)
//     + ONE ds_write_b64, replacing 16 bit-twiddle instrs + 4 ds_write_b16.
//   * exp2f -> __builtin_amdgcn_exp2f (guaranteed single v_exp_f32, no OCML).
//   * node-sum now cross-lane: 4x shfl_xor at the end (one-time).
// R12: resubmission (infra failure; kernel re-audited, unchanged).

#define T_STEPS 64
#define N_NODES 20000
#define F_INP   3
#define HD      64
#define G4      256    // 4*HD
#define KP      104    // padded bf16 K-stride: 0..63 H, 64..66 x, 67..103 zero
#define BM      16     // nodes per block == one M-tile
#define NBLK    1250   // N_NODES / BM
#define NTHR    256

typedef __attribute__((ext_vector_type(8))) short  bf16x8;
typedef __attribute__((ext_vector_type(4))) float  f32x4;
typedef __attribute__((ext_vector_type(4))) __bf16 bf16v4;

#define SC1 (-1.4426950408889634f)   // -log2(e)   : sigmoid gates (i,f,o)
#define SC2 (-2.8853900817779268f)   // -2*log2(e) : tanh pre-scale (c gate)

__device__ __forceinline__ unsigned short f2bf(float f) {
    union { float f; unsigned u; } v; v.f = f;
    unsigned r = v.u + 0x7FFFu + ((v.u >> 16) & 1u);   // RNE
    return (unsigned short)(r >> 16);
}
__device__ __forceinline__ float exp2fast(float x) {
    return __builtin_amdgcn_exp2f(x);                  // v_exp_f32, 1 instr
}

__global__ __launch_bounds__(NTHR, 4)
void gclstm_main(const float* __restrict__ x_seq,    // [T][N][3]
                 const float* __restrict__ W_x,      // [3][256]
                 const float* __restrict__ Theta,    // [64][256]
                 const float* __restrict__ b_conv,   // [256]
                 const float* __restrict__ b_gate,   // [256]
                 const float* __restrict__ w_ci,     // [64]
                 const float* __restrict__ w_cf,     // [64]
                 const float* __restrict__ w_co,     // [64]
                 float* __restrict__ partial)        // [NBLK][HD]
{
    __shared__ __align__(16) unsigned short Ts[HD * KP];     // 13312 B staging
    __shared__ __align__(16) unsigned short Al[2][BM * KP];  // 2 x 3328 B dbuf

    const int t   = threadIdx.x;
    const int blk = blockIdx.x;
    const int n0  = blk * BM;
    const int w   = t >> 6;        // wave 0..3 -> 16-dim group
    const int l   = t & 63;        // lane
    const int ln  = l & 15;        // NODE index (B-col) / Breg A-row
    const int lg  = l >> 4;        // k-octet select / C-row group
    const int d   = w * 16 + ln;   // Breg load dim (A-row ln -> dim w*16+ln)
    const int db  = w * 16 + lg * 4;  // gates-phase dim base (dims db..db+3)

    // ---- zero LDS: Ts (k-pad rows must stay 0), Al both buffers ----
    for (int i = t; i < (HD * KP) / 2; i += NTHR) ((unsigned*)Ts)[i] = 0u;
    for (int i = t; i < BM * KP; i += NTHR) ((unsigned*)&Al[0][0])[i] = 0u;
    __syncthreads();

    // x(ts=0) -> Al[0] k-rows 64..66 (visibility covered by chunk barriers)
    if (t < BM * F_INP)
        Al[0][(t / 3) * KP + 64 + (t % 3)] = f2bf(x_seq[(size_t)n0 * F_INP + t]);

    // ---- Theta/W_x -> Breg via 4 gate-chunks (scale folded into bf16) ----
    // Breg[g][ks] serves as the A-fragment: lane ln -> A-row ln -> dim w*16+ln,
    // k-octet lg. Load code identical to the validated B-frag load.
    bf16x8 Breg[4][3];
    #pragma unroll
    for (int g = 0; g < 4; ++g) {
        const float sc = (g == 2) ? SC2 : SC1;
        __syncthreads();                       // prior chunk's Breg reads done
        for (int i = t; i < HD * 64; i += NTHR) {          // Theta cols g*64..+63
            int k = i >> 6, j = i & 63;
            Ts[j * KP + k] = f2bf(sc * Theta[k * G4 + g * 64 + j]);
        }
        for (int i = t; i < F_INP * 64; i += NTHR) {       // W_x rows -> k 64..66
            int k = i >> 6, j = i & 63;
            Ts[j * KP + 64 + k] = f2bf(sc * W_x[k * G4 + g * 64 + j]);
        }
        __syncthreads();
        #pragma unroll
        for (int ks = 0; ks < 3; ++ks)
            Breg[g][ks] = *reinterpret_cast<const bf16x8*>(
                &Ts[d * KP + ks * 32 + lg * 8]);
    }

    // scaled biases + peephole for this lane's 4 dims db..db+3 (fp32, exact)
    float bI[4], bF[4], bC[4], bO[4], wci_[4], wcf_[4], wco_[4];
    #pragma unroll
    for (int r = 0; r < 4; ++r) {
        const int dd = db + r;
        bI[r] = SC1 * (b_conv[dd]       + b_gate[dd]);
        bF[r] = SC1 * (b_conv[64 + dd]  + b_gate[64 + dd]);
        bC[r] = SC2 * (b_conv[128 + dd] + b_gate[128 + dd]);
        bO[r] = SC1 * (b_conv[192 + dd] + b_gate[192 + dd]);
        wci_[r] = SC1 * w_ci[dd];
        wcf_[r] = SC1 * w_cf[dd];
        wco_[r] = SC1 * w_co[dd];
    }

    float creg[4] = {0.f, 0.f, 0.f, 0.f};   // C for (node=ln, dim=db+r)
    float hs[4]   = {0.f, 0.f, 0.f, 0.f};   // final-H values (node=ln, dim=db+r)
    const float* xp = x_seq + (size_t)N_NODES * F_INP + (size_t)n0 * F_INP; // ts=1

    for (int ts = 0; ts < T_STEPS; ++ts) {
        const unsigned short* Ard = &Al[ts & 1][0];
        unsigned short*       Awr = &Al[(ts & 1) ^ 1][0];

        // T14 part 1: issue next-timestep x load; hides under GEMM+gates.
        float xv = 0.0f;
        if (ts + 1 < T_STEPS && t < BM * F_INP) xv = xp[t];

        // ---- GEMM with bias-in-acc init (per-r bias: dim db+r) ----
        f32x4 acc[4];
        acc[0] = (f32x4){bI[0], bI[1], bI[2], bI[3]};
        acc[1] = (f32x4){bF[0], bF[1], bF[2], bF[3]};
        acc[2] = (f32x4){bC[0], bC[1], bC[2], bC[3]};
        acc[3] = (f32x4){bO[0], bO[1], bO[2], bO[3]};

        #pragma unroll
        for (int ks = 0; ks < 3; ++ks) {
            bf16x8 Ar = *reinterpret_cast<const bf16x8*>(
                &Ard[ln * KP + ks * 32 + lg * 8]);   // B-frag: H[node=ln][k]
            #pragma unroll
            for (int g = 0; g < 4; ++g)
                acc[g] = __builtin_amdgcn_mfma_f32_16x16x32_bf16(
                    Breg[g][ks], Ar, acc[g], 0, 0, 0);   // SWAPPED operands
        }
        // no barrier: gates write the OTHER buffer

        // ---- gates. D layout: col=ln (node), row=lg*4+r -> dim db+r ----
        bf16v4 hv;
        #pragma unroll
        for (int r = 0; r < 4; ++r) {
            float C   = creg[r];
            float giS = fmaf(wci_[r], C, acc[0][r]);
            float gfS = fmaf(wcf_[r], C, acc[1][r]);
            float I   = __builtin_amdgcn_rcpf(1.0f + exp2fast(giS));
            float Fg  = __builtin_amdgcn_rcpf(1.0f + exp2fast(gfS));
            float Tc  = fmaf(2.0f, __builtin_amdgcn_rcpf(1.0f + exp2fast(acc[2][r])), -1.0f);
            float Cn  = fmaf(Fg, C, I * Tc);
            float goS = fmaf(wco_[r], Cn, acc[3][r]);
            float O   = __builtin_amdgcn_rcpf(1.0f + exp2fast(goS));
            float th  = fmaf(2.0f, __builtin_amdgcn_rcpf(1.0f + exp2fast(SC2 * Cn)), -1.0f);
            float Hn  = O * th;
            creg[r] = Cn;
            hv[r]   = (__bf16)Hn;                 // pairs fuse to v_cvt_pk_bf16_f32
            if (ts == T_STEPS - 1) hs[r] = Hn;    // uniform branch, last step only
        }
        // ONE 8-byte LDS write: H_new[node=ln][db..db+3] (k<=63, disjoint from x)
        *reinterpret_cast<bf16v4*>(&Awr[ln * KP + db]) = hv;

        // T14 part 2: write the (already-arrived) x value to LDS (k 64..66).
        if (ts + 1 < T_STEPS && t < BM * F_INP)
            Awr[(t / 3) * KP + 64 + (t % 3)] = f2bf(xv);
        xp += (size_t)N_NODES * F_INP;
        __syncthreads();   // next-buf writes visible before next GEMM
    }

    // ---- node-sum: lanes ln=0..15 (same w,lg) hold the 16 nodes of dim db+r ----
    #pragma unroll
    for (int r = 0; r < 4; ++r) {
        hs[r] += __shfl_xor(hs[r], 1);
        hs[r] += __shfl_xor(hs[r], 2);
        hs[r] += __shfl_xor(hs[r], 4);
        hs[r] += __shfl_xor(hs[r], 8);
    }
    if (ln == 0) {
        #pragma unroll
        for (int r = 0; r < 4; ++r)
            partial[blk * HD + db + r] = hs[r];
    }
}

__global__ __launch_bounds__(NTHR, 1)
void reduce_head(const float* __restrict__ partial,  // [NBLK][HD]
                 const float* __restrict__ W_lin,    // [64][2]
                 const float* __restrict__ b_lin,    // [2]
                 float* __restrict__ out)            // [2]
{
    // float4 over dims: thread owns dim-quad dq, strides blocks by 16.
    __shared__ float4 sums[16][16];   // [p][dq]
    __shared__ float emb[HD];
    const int t  = threadIdx.x;       // 256 threads
    const int dq = t & 15;            // dim quad
    const int p  = t >> 4;            // 16-way split over node-blocks
    const float4* p4 = (const float4*)partial;   // [NBLK][16] float4
    float4 a = {0.f, 0.f, 0.f, 0.f};
    #pragma unroll 4
    for (int b = p; b < NBLK; b += 16) {
        float4 v = p4[b * 16 + dq];
        a.x += v.x; a.y += v.y; a.z += v.z; a.w += v.w;
    }
    sums[p][dq] = a;
    __syncthreads();
    if (t < 16) {
        float4 s = sums[0][t];
        #pragma unroll
        for (int q = 1; q < 16; ++q) {
            float4 v = sums[q][t];
            s.x += v.x; s.y += v.y; s.z += v.z; s.w += v.w;
        }
        const float inv = 1.0f / (float)N_NODES;
        emb[t * 4 + 0] = s.x * inv;
        emb[t * 4 + 1] = s.y * inv;
        emb[t * 4 + 2] = s.z * inv;
        emb[t * 4 + 3] = s.w * inv;
    }
    __syncthreads();
    if (t < 2) {
        float acc = b_lin[t];
        #pragma unroll
        for (int dd = 0; dd < HD; ++dd)
            acc = fmaf(emb[dd], W_lin[dd * 2 + t], acc);
        out[t] = acc;
    }
}

extern "C" void kernel_launch(void* const* d_in, const int* in_sizes, int n_in,
                              void* d_out, int out_size, void* d_ws, size_t ws_size,
                              hipStream_t stream) {
    const float* x_seq  = (const float*)d_in[0];
    // d_in[1] = edge_index (int64) -- unused: ChebConv K=1 has no neighbor aggregation
    const float* W_x    = (const float*)d_in[2];
    const float* Theta  = (const float*)d_in[3];
    const float* b_conv = (const float*)d_in[4];
    const float* b_gate = (const float*)d_in[5];
    const float* w_ci   = (const float*)d_in[6];
    const float* w_cf   = (const float*)d_in[7];
    const float* w_co   = (const float*)d_in[8];
    const float* W_lin  = (const float*)d_in[9];
    const float* b_lin  = (const float*)d_in[10];

    float* out     = (float*)d_out;
    float* partial = (float*)d_ws;   // NBLK*HD floats = 320000 B

    gclstm_main<<<NBLK, NTHR, 0, stream>>>(x_seq, W_x, Theta, b_conv, b_gate,
                                           w_ci, w_cf, w_co, partial);
    reduce_head<<<1, NTHR, 0, stream>>>(partial, W_lin, b_lin, out);
}